// Round 6
// baseline (255.401 us; speedup 1.0000x reference)
//
#include <hip/hip_runtime.h>
#include <hip/hip_bf16.h>

// CPPN via bf16 MFMA, round 6:
// (a) activation dispatch truly scalarized: sid/purity go through
//     readfirstlane so the compiler KNOWS they're uniform -> s_cmp/s_cbranch
//     (scalar pipe) instead of exec-mask cascades (round 5's mistake).
// (b) NT=8 -> 2048 blocks = 8 blocks/CU = 32 waves/CU (round 5 was
//     grid-limited to 16) + __launch_bounds__(256,8) to hide the serial
//     pack->MFMA->act chain latency.

#define BLK 256
#define NT 8  // 8 16-pixel tiles per wave -> 128 px/wave, 512 px/block

constexpr int NIN = 12, HID = 32, NOUT = 3;

typedef __attribute__((ext_vector_type(8))) short short8v;
typedef __attribute__((ext_vector_type(4))) float f32x4;
typedef __attribute__((ext_vector_type(4))) unsigned uint4v;

__device__ __forceinline__ unsigned short f2bf(float f) {  // setup only
    unsigned u = __builtin_bit_cast(unsigned, f);
    u += 0x7FFFu + ((u >> 16) & 1u);  // RNE
    return (unsigned short)(u >> 16);
}

__device__ __forceinline__ unsigned pk2(float lo, float hi) {
    __hip_bfloat162 h = __float22bfloat162_rn(make_float2(lo, hi));
    unsigned r; __builtin_memcpy(&r, &h, 4);
    return r;
}

__device__ __forceinline__ float tanh_fast(float x) {
    float e = __expf(2.0f * x);
    return 1.0f - 2.0f * __builtin_amdgcn_rcpf(e + 1.0f);
}

// sid is a readfirstlane result (compiler-known uniform) -> scalar branches.
__device__ __forceinline__ float act_uniform(float x, int sid) {
    if (sid == 0) return x;
    if (sid == 1) return tanh_fast(x);
    if (sid == 2) return __builtin_amdgcn_rcpf(1.0f + __expf(-x));
    if (sid == 3) return __sinf(x);
    return __expf(-0.5f * x * x);  // gaussian
}

// Per-lane fallback (impure slots) — branchless, proven in round 4.
__device__ __forceinline__ float act_lane(float x, int id) {
    float e_in = (id == 1) ? (x + x) : ((id == 4) ? (-0.5f * x * x) : -x);
    float e = __expf(e_in);
    float r = __builtin_amdgcn_rcpf(e + 1.0f);
    float res = x;
    res = (id == 1) ? fmaf(-2.0f, r, 1.0f) : res;
    res = (id == 2) ? r : res;
    res = (id == 3) ? __sinf(x) : res;
    res = (id == 4) ? e : res;
    return res;
}

template <bool GUARD>
__global__ void __launch_bounds__(BLK, 8) cppn_mfma(
    const float* __restrict__ xin, const float* __restrict__ bin,
    const float* __restrict__ W1, const float* __restrict__ b1, const int* __restrict__ a1,
    const float* __restrict__ W2, const float* __restrict__ b2, const int* __restrict__ a2,
    const float* __restrict__ W3, const float* __restrict__ b3, const int* __restrict__ a3,
    const float* __restrict__ Wo, const float* __restrict__ bo,
    float* __restrict__ out, int Ppix, int pxBase) {
    const int tid = threadIdx.x;
    const int lane = tid & 63;
    const int wid = tid >> 6;
    const int q = lane >> 4;
    const int l15 = lane & 15;
    const int n = lane & 31;

    // ---- node permutation per layer: stable sort by act id; scrambled so
    // D-slot group (t,r) = sorted positions 16t+4r+{0..3} (consecutive run) ----
    auto build_perm = [&](const int* __restrict__ a) -> int {
        int myid = a[n];
        unsigned m0 = (unsigned)__ballot(myid == 0);
        unsigned m1 = (unsigned)__ballot(myid == 1);
        unsigned m2 = (unsigned)__ballot(myid == 2);
        unsigned m3 = (unsigned)__ballot(myid == 3);
        unsigned m4 = (unsigned)__ballot(myid == 4);
        int c0 = __popc(m0), c1 = __popc(m1), c2 = __popc(m2), c3 = __popc(m3);
        int pre = 0;
        pre = (myid == 1) ? c0 : pre;
        pre = (myid == 2) ? c0 + c1 : pre;
        pre = (myid == 3) ? c0 + c1 + c2 : pre;
        pre = (myid == 4) ? c0 + c1 + c2 + c3 : pre;
        unsigned mm = m0;
        mm = (myid == 1) ? m1 : mm;
        mm = (myid == 2) ? m2 : mm;
        mm = (myid == 3) ? m3 : mm;
        mm = (myid == 4) ? m4 : mm;
        unsigned lt = (1u << n) - 1u;
        int pos = pre + __popc(mm & lt);  // stable rank, bijective 0..31
        int npr = ((pos >> 4) << 4) + ((pos & 3) << 2) + ((pos >> 2) & 3);
        int perm = __builtin_amdgcn_ds_permute(npr << 2, n);  // perm[new]=orig
        return perm & 31;
    };
    const int perm1 = build_perm(a1);
    const int perm2 = build_perm(a2);
    const int perm3 = build_perm(a3);

    auto pat = [&](int permv, int idx) -> int {
        return __builtin_amdgcn_ds_bpermute(idx << 2, permv) & 31;
    };

    // ---- fragment construction (one-time) ----
    int o1[2], o2[2], o3[2];
#pragma unroll
    for (int t = 0; t < 2; ++t) {
        o1[t] = pat(perm1, 16 * t + l15);
        o2[t] = pat(perm2, 16 * t + l15);
        o3[t] = pat(perm3, 16 * t + l15);
    }
    int i2v[8], i3v[8], iov[8];
#pragma unroll
    for (int j = 0; j < 8; ++j) {
        int kk = 16 * (j >> 2) + 4 * q + (j & 3);  // mu2 k-slot mapping
        i2v[j] = pat(perm1, kk);
        i3v[j] = pat(perm2, kk);
        iov[j] = pat(perm3, kk);
    }
    short8v w1f[2], w2f[2], w3f[2], wof;
#pragma unroll
    for (int t = 0; t < 2; ++t) {
#pragma unroll
        for (int j = 0; j < 8; ++j) {
            int k1 = 8 * q + j;  // mu1: inputs unpermuted
            float v1 = (k1 < NIN) ? W1[k1 * HID + o1[t]]
                     : (k1 == NIN ? b1[o1[t]] : 0.0f);
            w1f[t][j] = (short)f2bf(v1);
            w2f[t][j] = (short)f2bf(W2[i2v[j] * HID + o2[t]]);
            w3f[t][j] = (short)f2bf(W3[i3v[j] * HID + o3[t]]);
        }
    }
#pragma unroll
    for (int j = 0; j < 8; ++j)
        wof[j] = (l15 < NOUT) ? (short)f2bf(Wo[iov[j] * NOUT + l15]) : (short)0;

    f32x4 b2f[2], b3f[2], bof;
    unsigned av1 = 0, av2 = 0, av3 = 0;  // per-lane 4-bit act ids (fallback)
#pragma unroll
    for (int e = 0; e < 8; ++e) {
        int t = e >> 2, r = e & 3;
        int idx = 16 * t + 4 * q + r;
        int p1i = pat(perm1, idx), p2i = pat(perm2, idx), p3i = pat(perm3, idx);
        b2f[t][r] = b2[p2i];
        b3f[t][r] = b3[p3i];
        av1 |= (unsigned)(a1[p1i] & 15) << (4 * e);
        av2 |= (unsigned)(a2[p2i] & 15) << (4 * e);
        av3 |= (unsigned)(a3[p3i] & 15) << (4 * e);
    }
#pragma unroll
    for (int r = 0; r < 4; ++r) bof[r] = (q == 0 && r < NOUT) ? bo[r] : 0.0f;

    // ---- per-slot uniform id + purity, then FORCE scalar (readfirstlane) ----
    int idn1 = a1[perm1], idn2 = a2[perm2], idn3 = a3[perm3];
    unsigned sidw1 = 0, sidw2 = 0, sidw3 = 0, prw1 = 0, prw2 = 0, prw3 = 0;
#pragma unroll
    for (int e = 0; e < 8; ++e) {
        int g = 16 * (e >> 2) + (e & 3);
        {
            int s0 = __builtin_amdgcn_readlane(idn1, g);
            int s1 = __builtin_amdgcn_readlane(idn1, g + 4);
            int s2 = __builtin_amdgcn_readlane(idn1, g + 8);
            int s3 = __builtin_amdgcn_readlane(idn1, g + 12);
            sidw1 |= (unsigned)(s0 & 15) << (4 * e);
            prw1 |= (unsigned)((s0 == s1) & (s0 == s2) & (s0 == s3)) << e;
        }
        {
            int s0 = __builtin_amdgcn_readlane(idn2, g);
            int s1 = __builtin_amdgcn_readlane(idn2, g + 4);
            int s2 = __builtin_amdgcn_readlane(idn2, g + 8);
            int s3 = __builtin_amdgcn_readlane(idn2, g + 12);
            sidw2 |= (unsigned)(s0 & 15) << (4 * e);
            prw2 |= (unsigned)((s0 == s1) & (s0 == s2) & (s0 == s3)) << e;
        }
        {
            int s0 = __builtin_amdgcn_readlane(idn3, g);
            int s1 = __builtin_amdgcn_readlane(idn3, g + 4);
            int s2 = __builtin_amdgcn_readlane(idn3, g + 8);
            int s3 = __builtin_amdgcn_readlane(idn3, g + 12);
            sidw3 |= (unsigned)(s0 & 15) << (4 * e);
            prw3 |= (unsigned)((s0 == s1) & (s0 == s2) & (s0 == s3)) << e;
        }
    }
    // The key fix vs round 5: these are now compiler-known-uniform scalars,
    // so every act branch below is s_cmp/s_cbranch, not exec-mask cascades.
    const unsigned S1 = (unsigned)__builtin_amdgcn_readfirstlane((int)sidw1);
    const unsigned S2 = (unsigned)__builtin_amdgcn_readfirstlane((int)sidw2);
    const unsigned S3 = (unsigned)__builtin_amdgcn_readfirstlane((int)sidw3);
    const unsigned P1 = (unsigned)__builtin_amdgcn_readfirstlane((int)prw1);
    const unsigned P2 = (unsigned)__builtin_amdgcn_readfirstlane((int)prw2);
    const unsigned P3 = (unsigned)__builtin_amdgcn_readfirstlane((int)prw3);

    auto actpack = [&](f32x4 p0, f32x4 p1, unsigned sS, unsigned sP,
                       unsigned av) -> uint4v {
        float h[8];
#pragma unroll
        for (int e = 0; e < 8; ++e) {
            float x = (e < 4) ? p0[e] : p1[e - 4];
            if ((sP >> e) & 1u) {                       // uniform -> s_cbranch
                int sid = (int)((sS >> (4 * e)) & 15u); // scalar
                h[e] = act_uniform(x, sid);
            } else {
                h[e] = act_lane(x, (int)((av >> (4 * e)) & 15u));
            }
        }
        uint4v w;
        w[0] = pk2(h[0], h[1]); w[1] = pk2(h[2], h[3]);
        w[2] = pk2(h[4], h[5]); w[3] = pk2(h[6], h[7]);
        return w;
    };

    float binv[8];
#pragma unroll
    for (int j = 0; j < 8; ++j) {
        int k = 8 * q + j;
        binv[j] = (k < NIN) ? bin[k] : 0.0f;
    }

    const long long wIdx = (long long)blockIdx.x * (BLK / 64) + wid;
    const long long px0 = (long long)pxBase + wIdx * (NT * 16);
    const float* __restrict__ xbase = xin + px0 * NIN;
    float* __restrict__ obase = out + px0 * 3;
    const f32x4 z = {0.0f, 0.0f, 0.0f, 0.0f};

#pragma unroll 1
    for (int it = 0; it < NT; ++it) {
        const int po = it * 16 + l15;
        const bool ok = !GUARD || (px0 + po < (long long)Ppix);

        uint4v b0w = {0, 0, 0, 0};
        if (q == 0) {
            if (ok) {
                const float4* ip = reinterpret_cast<const float4*>(xbase + po * NIN);
                float4 xa = ip[0], xb = ip[1];
                b0w[0] = pk2(xa.x + binv[0], xa.y + binv[1]);
                b0w[1] = pk2(xa.z + binv[2], xa.w + binv[3]);
                b0w[2] = pk2(xb.x + binv[4], xb.y + binv[5]);
                b0w[3] = pk2(xb.z + binv[6], xb.w + binv[7]);
            }
        } else if (q == 1) {
            if (ok) {
                float4 xc = reinterpret_cast<const float4*>(xbase + po * NIN)[2];
                b0w[0] = pk2(xc.x + binv[0], xc.y + binv[1]);
                b0w[1] = pk2(xc.z + binv[2], xc.w + binv[3]);
            }
            b0w[2] = 0x3F80u;  // constant-1 bias row (k=12)
        }

        short8v hb = __builtin_bit_cast(short8v, b0w);
        f32x4 p0 = __builtin_amdgcn_mfma_f32_16x16x32_bf16(w1f[0], hb, z, 0, 0, 0);
        f32x4 p1 = __builtin_amdgcn_mfma_f32_16x16x32_bf16(w1f[1], hb, z, 0, 0, 0);

        hb = __builtin_bit_cast(short8v, actpack(p0, p1, S1, P1, av1));
        p0 = __builtin_amdgcn_mfma_f32_16x16x32_bf16(w2f[0], hb, b2f[0], 0, 0, 0);
        p1 = __builtin_amdgcn_mfma_f32_16x16x32_bf16(w2f[1], hb, b2f[1], 0, 0, 0);

        hb = __builtin_bit_cast(short8v, actpack(p0, p1, S2, P2, av2));
        p0 = __builtin_amdgcn_mfma_f32_16x16x32_bf16(w3f[0], hb, b3f[0], 0, 0, 0);
        p1 = __builtin_amdgcn_mfma_f32_16x16x32_bf16(w3f[1], hb, b3f[1], 0, 0, 0);

        hb = __builtin_bit_cast(short8v, actpack(p0, p1, S3, P3, av3));
        f32x4 o4 = __builtin_amdgcn_mfma_f32_16x16x32_bf16(wof, hb, bof, 0, 0, 0);

        if (q == 0 && ok) {
            float* op = obase + po * 3;
            op[0] = tanh_fast(o4[0]);
            op[1] = tanh_fast(o4[1]);
            op[2] = tanh_fast(o4[2]);
        }
    }
}

extern "C" void kernel_launch(void* const* d_in, const int* in_sizes, int n_in,
                              void* d_out, int out_size, void* d_ws, size_t ws_size,
                              hipStream_t stream) {
    (void)n_in; (void)out_size; (void)d_ws; (void)ws_size;
    const float* xin = (const float*)d_in[0];
    const float* bin = (const float*)d_in[1];
    const float* W1  = (const float*)d_in[2];
    const float* b1  = (const float*)d_in[3];
    const int*   a1  = (const int*)  d_in[4];
    const float* W2  = (const float*)d_in[5];
    const float* b2  = (const float*)d_in[6];
    const int*   a2  = (const int*)  d_in[7];
    const float* W3  = (const float*)d_in[8];
    const float* b3  = (const float*)d_in[9];
    const int*   a3  = (const int*)  d_in[10];
    const float* Wo  = (const float*)d_in[11];
    const float* bo  = (const float*)d_in[12];
    float* out = (float*)d_out;

    const int Ppix = in_sizes[0] / NIN;
    const int pxPerBlock = (BLK / 64) * NT * 16;  // 512
    const int fullBlocks = Ppix / pxPerBlock;
    const int rem = Ppix - fullBlocks * pxPerBlock;
    if (fullBlocks > 0)
        hipLaunchKernelGGL((cppn_mfma<false>), dim3(fullBlocks), dim3(BLK), 0, stream,
                           xin, bin, W1, b1, a1, W2, b2, a2, W3, b3, a3, Wo, bo,
                           out, Ppix, 0);
    if (rem > 0)
        hipLaunchKernelGGL((cppn_mfma<true>), dim3(1), dim3(BLK), 0, stream,
                           xin, bin, W1, b1, a1, W2, b2, a2, W3, b3, a3, Wo, bo,
                           out, Ppix, fullBlocks * pxPerBlock);
}

// Round 7
// 197.199 us; speedup vs baseline: 1.2951x; 1.2951x over previous
//
#include <hip/hip_runtime.h>
#include <hip/hip_bf16.h>

// CPPN via bf16 MFMA, round 7:
// Round 6's __launch_bounds__(256,8) forced VGPR=32 -> weight fragments
// spilled to scratch (FETCH 24.8->224MB, WRITE 17->168MB, 10x HBM traffic).
// Fix: (BLK,4) cap = 128 VGPR; natural use ~64 VGPR ALREADY allows 8
// waves/SIMD in HW, so we keep round 6's occupancy win (NT=8 -> 2048 blocks
// = 8 blocks/CU) without the spills. Scalarized act dispatch kept.

#define BLK 256
#define NT 8  // 8 16-pixel tiles per wave -> 128 px/wave, 512 px/block

constexpr int NIN = 12, HID = 32, NOUT = 3;

typedef __attribute__((ext_vector_type(8))) short short8v;
typedef __attribute__((ext_vector_type(4))) float f32x4;
typedef __attribute__((ext_vector_type(4))) unsigned uint4v;

__device__ __forceinline__ unsigned short f2bf(float f) {  // setup only
    unsigned u = __builtin_bit_cast(unsigned, f);
    u += 0x7FFFu + ((u >> 16) & 1u);  // RNE
    return (unsigned short)(u >> 16);
}

__device__ __forceinline__ unsigned pk2(float lo, float hi) {
    __hip_bfloat162 h = __float22bfloat162_rn(make_float2(lo, hi));
    unsigned r; __builtin_memcpy(&r, &h, 4);
    return r;
}

__device__ __forceinline__ float tanh_fast(float x) {
    float e = __expf(2.0f * x);
    return 1.0f - 2.0f * __builtin_amdgcn_rcpf(e + 1.0f);
}

// sid is a readfirstlane result (compiler-known uniform) -> scalar branches.
__device__ __forceinline__ float act_uniform(float x, int sid) {
    if (sid == 0) return x;
    if (sid == 1) return tanh_fast(x);
    if (sid == 2) return __builtin_amdgcn_rcpf(1.0f + __expf(-x));
    if (sid == 3) return __sinf(x);
    return __expf(-0.5f * x * x);  // gaussian
}

// Per-lane fallback (impure slots) — branchless, proven in round 4.
__device__ __forceinline__ float act_lane(float x, int id) {
    float e_in = (id == 1) ? (x + x) : ((id == 4) ? (-0.5f * x * x) : -x);
    float e = __expf(e_in);
    float r = __builtin_amdgcn_rcpf(e + 1.0f);
    float res = x;
    res = (id == 1) ? fmaf(-2.0f, r, 1.0f) : res;
    res = (id == 2) ? r : res;
    res = (id == 3) ? __sinf(x) : res;
    res = (id == 4) ? e : res;
    return res;
}

template <bool GUARD>
__global__ void __launch_bounds__(BLK, 4) cppn_mfma(
    const float* __restrict__ xin, const float* __restrict__ bin,
    const float* __restrict__ W1, const float* __restrict__ b1, const int* __restrict__ a1,
    const float* __restrict__ W2, const float* __restrict__ b2, const int* __restrict__ a2,
    const float* __restrict__ W3, const float* __restrict__ b3, const int* __restrict__ a3,
    const float* __restrict__ Wo, const float* __restrict__ bo,
    float* __restrict__ out, int Ppix, int pxBase) {
    const int tid = threadIdx.x;
    const int lane = tid & 63;
    const int wid = tid >> 6;
    const int q = lane >> 4;
    const int l15 = lane & 15;
    const int n = lane & 31;

    // ---- node permutation per layer: stable sort by act id; scrambled so
    // D-slot group (t,r) = sorted positions 16t+4r+{0..3} (consecutive run) ----
    auto build_perm = [&](const int* __restrict__ a) -> int {
        int myid = a[n];
        unsigned m0 = (unsigned)__ballot(myid == 0);
        unsigned m1 = (unsigned)__ballot(myid == 1);
        unsigned m2 = (unsigned)__ballot(myid == 2);
        unsigned m3 = (unsigned)__ballot(myid == 3);
        unsigned m4 = (unsigned)__ballot(myid == 4);
        int c0 = __popc(m0), c1 = __popc(m1), c2 = __popc(m2), c3 = __popc(m3);
        int pre = 0;
        pre = (myid == 1) ? c0 : pre;
        pre = (myid == 2) ? c0 + c1 : pre;
        pre = (myid == 3) ? c0 + c1 + c2 : pre;
        pre = (myid == 4) ? c0 + c1 + c2 + c3 : pre;
        unsigned mm = m0;
        mm = (myid == 1) ? m1 : mm;
        mm = (myid == 2) ? m2 : mm;
        mm = (myid == 3) ? m3 : mm;
        mm = (myid == 4) ? m4 : mm;
        unsigned lt = (1u << n) - 1u;
        int pos = pre + __popc(mm & lt);  // stable rank, bijective 0..31
        int npr = ((pos >> 4) << 4) + ((pos & 3) << 2) + ((pos >> 2) & 3);
        int perm = __builtin_amdgcn_ds_permute(npr << 2, n);  // perm[new]=orig
        return perm & 31;
    };
    const int perm1 = build_perm(a1);
    const int perm2 = build_perm(a2);
    const int perm3 = build_perm(a3);

    auto pat = [&](int permv, int idx) -> int {
        return __builtin_amdgcn_ds_bpermute(idx << 2, permv) & 31;
    };

    // ---- fragment construction (one-time) ----
    int o1[2], o2[2], o3[2];
#pragma unroll
    for (int t = 0; t < 2; ++t) {
        o1[t] = pat(perm1, 16 * t + l15);
        o2[t] = pat(perm2, 16 * t + l15);
        o3[t] = pat(perm3, 16 * t + l15);
    }
    int i2v[8], i3v[8], iov[8];
#pragma unroll
    for (int j = 0; j < 8; ++j) {
        int kk = 16 * (j >> 2) + 4 * q + (j & 3);  // mu2 k-slot mapping
        i2v[j] = pat(perm1, kk);
        i3v[j] = pat(perm2, kk);
        iov[j] = pat(perm3, kk);
    }
    short8v w1f[2], w2f[2], w3f[2], wof;
#pragma unroll
    for (int t = 0; t < 2; ++t) {
#pragma unroll
        for (int j = 0; j < 8; ++j) {
            int k1 = 8 * q + j;  // mu1: inputs unpermuted
            float v1 = (k1 < NIN) ? W1[k1 * HID + o1[t]]
                     : (k1 == NIN ? b1[o1[t]] : 0.0f);
            w1f[t][j] = (short)f2bf(v1);
            w2f[t][j] = (short)f2bf(W2[i2v[j] * HID + o2[t]]);
            w3f[t][j] = (short)f2bf(W3[i3v[j] * HID + o3[t]]);
        }
    }
#pragma unroll
    for (int j = 0; j < 8; ++j)
        wof[j] = (l15 < NOUT) ? (short)f2bf(Wo[iov[j] * NOUT + l15]) : (short)0;

    f32x4 b2f[2], b3f[2], bof;
    unsigned av1 = 0, av2 = 0, av3 = 0;  // per-lane 4-bit act ids (fallback)
#pragma unroll
    for (int e = 0; e < 8; ++e) {
        int t = e >> 2, r = e & 3;
        int idx = 16 * t + 4 * q + r;
        int p1i = pat(perm1, idx), p2i = pat(perm2, idx), p3i = pat(perm3, idx);
        b2f[t][r] = b2[p2i];
        b3f[t][r] = b3[p3i];
        av1 |= (unsigned)(a1[p1i] & 15) << (4 * e);
        av2 |= (unsigned)(a2[p2i] & 15) << (4 * e);
        av3 |= (unsigned)(a3[p3i] & 15) << (4 * e);
    }
#pragma unroll
    for (int r = 0; r < 4; ++r) bof[r] = (q == 0 && r < NOUT) ? bo[r] : 0.0f;

    // ---- per-slot uniform id + purity, then FORCE scalar (readfirstlane) ----
    int idn1 = a1[perm1], idn2 = a2[perm2], idn3 = a3[perm3];
    unsigned sidw1 = 0, sidw2 = 0, sidw3 = 0, prw1 = 0, prw2 = 0, prw3 = 0;
#pragma unroll
    for (int e = 0; e < 8; ++e) {
        int g = 16 * (e >> 2) + (e & 3);
        {
            int s0 = __builtin_amdgcn_readlane(idn1, g);
            int s1 = __builtin_amdgcn_readlane(idn1, g + 4);
            int s2 = __builtin_amdgcn_readlane(idn1, g + 8);
            int s3 = __builtin_amdgcn_readlane(idn1, g + 12);
            sidw1 |= (unsigned)(s0 & 15) << (4 * e);
            prw1 |= (unsigned)((s0 == s1) & (s0 == s2) & (s0 == s3)) << e;
        }
        {
            int s0 = __builtin_amdgcn_readlane(idn2, g);
            int s1 = __builtin_amdgcn_readlane(idn2, g + 4);
            int s2 = __builtin_amdgcn_readlane(idn2, g + 8);
            int s3 = __builtin_amdgcn_readlane(idn2, g + 12);
            sidw2 |= (unsigned)(s0 & 15) << (4 * e);
            prw2 |= (unsigned)((s0 == s1) & (s0 == s2) & (s0 == s3)) << e;
        }
        {
            int s0 = __builtin_amdgcn_readlane(idn3, g);
            int s1 = __builtin_amdgcn_readlane(idn3, g + 4);
            int s2 = __builtin_amdgcn_readlane(idn3, g + 8);
            int s3 = __builtin_amdgcn_readlane(idn3, g + 12);
            sidw3 |= (unsigned)(s0 & 15) << (4 * e);
            prw3 |= (unsigned)((s0 == s1) & (s0 == s2) & (s0 == s3)) << e;
        }
    }
    // Compiler-known-uniform scalars -> act branches are s_cmp/s_cbranch.
    const unsigned S1 = (unsigned)__builtin_amdgcn_readfirstlane((int)sidw1);
    const unsigned S2 = (unsigned)__builtin_amdgcn_readfirstlane((int)sidw2);
    const unsigned S3 = (unsigned)__builtin_amdgcn_readfirstlane((int)sidw3);
    const unsigned P1 = (unsigned)__builtin_amdgcn_readfirstlane((int)prw1);
    const unsigned P2 = (unsigned)__builtin_amdgcn_readfirstlane((int)prw2);
    const unsigned P3 = (unsigned)__builtin_amdgcn_readfirstlane((int)prw3);

    auto actpack = [&](f32x4 p0, f32x4 p1, unsigned sS, unsigned sP,
                       unsigned av) -> uint4v {
        float h[8];
#pragma unroll
        for (int e = 0; e < 8; ++e) {
            float x = (e < 4) ? p0[e] : p1[e - 4];
            if ((sP >> e) & 1u) {                       // uniform -> s_cbranch
                int sid = (int)((sS >> (4 * e)) & 15u); // scalar
                h[e] = act_uniform(x, sid);
            } else {
                h[e] = act_lane(x, (int)((av >> (4 * e)) & 15u));
            }
        }
        uint4v w;
        w[0] = pk2(h[0], h[1]); w[1] = pk2(h[2], h[3]);
        w[2] = pk2(h[4], h[5]); w[3] = pk2(h[6], h[7]);
        return w;
    };

    float binv[8];
#pragma unroll
    for (int j = 0; j < 8; ++j) {
        int k = 8 * q + j;
        binv[j] = (k < NIN) ? bin[k] : 0.0f;
    }

    const long long wIdx = (long long)blockIdx.x * (BLK / 64) + wid;
    const long long px0 = (long long)pxBase + wIdx * (NT * 16);
    const float* __restrict__ xbase = xin + px0 * NIN;
    float* __restrict__ obase = out + px0 * 3;
    const f32x4 z = {0.0f, 0.0f, 0.0f, 0.0f};

#pragma unroll 1
    for (int it = 0; it < NT; ++it) {
        const int po = it * 16 + l15;
        const bool ok = !GUARD || (px0 + po < (long long)Ppix);

        uint4v b0w = {0, 0, 0, 0};
        if (q == 0) {
            if (ok) {
                const float4* ip = reinterpret_cast<const float4*>(xbase + po * NIN);
                float4 xa = ip[0], xb = ip[1];
                b0w[0] = pk2(xa.x + binv[0], xa.y + binv[1]);
                b0w[1] = pk2(xa.z + binv[2], xa.w + binv[3]);
                b0w[2] = pk2(xb.x + binv[4], xb.y + binv[5]);
                b0w[3] = pk2(xb.z + binv[6], xb.w + binv[7]);
            }
        } else if (q == 1) {
            if (ok) {
                float4 xc = reinterpret_cast<const float4*>(xbase + po * NIN)[2];
                b0w[0] = pk2(xc.x + binv[0], xc.y + binv[1]);
                b0w[1] = pk2(xc.z + binv[2], xc.w + binv[3]);
            }
            b0w[2] = 0x3F80u;  // constant-1 bias row (k=12)
        }

        short8v hb = __builtin_bit_cast(short8v, b0w);
        f32x4 p0 = __builtin_amdgcn_mfma_f32_16x16x32_bf16(w1f[0], hb, z, 0, 0, 0);
        f32x4 p1 = __builtin_amdgcn_mfma_f32_16x16x32_bf16(w1f[1], hb, z, 0, 0, 0);

        hb = __builtin_bit_cast(short8v, actpack(p0, p1, S1, P1, av1));
        p0 = __builtin_amdgcn_mfma_f32_16x16x32_bf16(w2f[0], hb, b2f[0], 0, 0, 0);
        p1 = __builtin_amdgcn_mfma_f32_16x16x32_bf16(w2f[1], hb, b2f[1], 0, 0, 0);

        hb = __builtin_bit_cast(short8v, actpack(p0, p1, S2, P2, av2));
        p0 = __builtin_amdgcn_mfma_f32_16x16x32_bf16(w3f[0], hb, b3f[0], 0, 0, 0);
        p1 = __builtin_amdgcn_mfma_f32_16x16x32_bf16(w3f[1], hb, b3f[1], 0, 0, 0);

        hb = __builtin_bit_cast(short8v, actpack(p0, p1, S3, P3, av3));
        f32x4 o4 = __builtin_amdgcn_mfma_f32_16x16x32_bf16(wof, hb, bof, 0, 0, 0);

        if (q == 0 && ok) {
            float* op = obase + po * 3;
            op[0] = tanh_fast(o4[0]);
            op[1] = tanh_fast(o4[1]);
            op[2] = tanh_fast(o4[2]);
        }
    }
}

extern "C" void kernel_launch(void* const* d_in, const int* in_sizes, int n_in,
                              void* d_out, int out_size, void* d_ws, size_t ws_size,
                              hipStream_t stream) {
    (void)n_in; (void)out_size; (void)d_ws; (void)ws_size;
    const float* xin = (const float*)d_in[0];
    const float* bin = (const float*)d_in[1];
    const float* W1  = (const float*)d_in[2];
    const float* b1  = (const float*)d_in[3];
    const int*   a1  = (const int*)  d_in[4];
    const float* W2  = (const float*)d_in[5];
    const float* b2  = (const float*)d_in[6];
    const int*   a2  = (const int*)  d_in[7];
    const float* W3  = (const float*)d_in[8];
    const float* b3  = (const float*)d_in[9];
    const int*   a3  = (const int*)  d_in[10];
    const float* Wo  = (const float*)d_in[11];
    const float* bo  = (const float*)d_in[12];
    float* out = (float*)d_out;

    const int Ppix = in_sizes[0] / NIN;
    const int pxPerBlock = (BLK / 64) * NT * 16;  // 512
    const int fullBlocks = Ppix / pxPerBlock;
    const int rem = Ppix - fullBlocks * pxPerBlock;
    if (fullBlocks > 0)
        hipLaunchKernelGGL((cppn_mfma<false>), dim3(fullBlocks), dim3(BLK), 0, stream,
                           xin, bin, W1, b1, a1, W2, b2, a2, W3, b3, a3, Wo, bo,
                           out, Ppix, 0);
    if (rem > 0)
        hipLaunchKernelGGL((cppn_mfma<true>), dim3(1), dim3(BLK), 0, stream,
                           xin, bin, W1, b1, a1, W2, b2, a2, W3, b3, a3, Wo, bo,
                           out, Ppix, fullBlocks * pxPerBlock);
}

// Round 10
// 189.503 us; speedup vs baseline: 1.3477x; 1.0406x over previous
//
#include <hip/hip_runtime.h>
#include <hip/hip_bf16.h>

// CPPN via bf16 MFMA, round 8: DETERMINISTIC branchless activation chain.
// Rounds 5-7 showed the pure/impure + 5-way-branch act dispatch gets
// if-converted (both paths, all cases computed: ~2500 VALU cyc/tile vs ~450
// essential). Fix: one branchless select-chain per element (compiler can't
// add work to selects): shared exp2 (v_exp IS exp2) for tanh/sigmoid/gauss,
// one __sinf, 4 v_cmp + 5 cndmask. Packs via inline-asm v_cvt_pk_bf16_f32
// (1 instr vs ~10 for the library RNE emulation). Sort/permute/readlane
// machinery dropped (per-lane compares are exact without it). NT=16.

#define BLK 256
#define NT 16  // 16-pixel tiles per wave -> 256 px/wave, 1024 px/block

constexpr int NIN = 12, HID = 32, NOUT = 3;

typedef __attribute__((ext_vector_type(8))) short short8v;
typedef __attribute__((ext_vector_type(4))) float f32x4;
typedef __attribute__((ext_vector_type(4))) unsigned uint4v;

__device__ __forceinline__ unsigned short f2bf(float f) {  // setup only
    unsigned u = __builtin_bit_cast(unsigned, f);
    u += 0x7FFFu + ((u >> 16) & 1u);  // RNE
    return (unsigned short)(u >> 16);
}

// Single-instruction packed f32->bf16x2 (RNE on gfx950).
__device__ __forceinline__ unsigned cvt_pk(float lo, float hi) {
    unsigned r;
    asm("v_cvt_pk_bf16_f32 %0, %1, %2" : "=v"(r) : "v"(lo), "v"(hi));
    return r;
}

__device__ __forceinline__ float tanh_fast(float x) {
    float e = __expf(2.0f * x);
    return 1.0f - 2.0f * __builtin_amdgcn_rcpf(e + 1.0f);
}

// Branchless: exactly one of sid 0..4; y via select chain. exp folded to
// native exp2 (L = log2 e). No branches -> codegen is what you see.
__device__ __forceinline__ float act_chain(float x, int sid) {
    const float L = 1.4426950408889634f;
    const bool is1 = (sid == 1), is2 = (sid == 2), is3 = (sid == 3), is4 = (sid == 4);
    float u = x * L;
    float ein = is1 ? (u + u) : -u;          // tanh: 2Lx ; sig/id/sin: -Lx
    float g = (u * -0.5f) * x;               // gauss: -0.5*L*x^2
    ein = is4 ? g : ein;
    float e = exp2f(ein);                    // v_exp_f32
    float r = __builtin_amdgcn_rcpf(e + 1.0f);
    float y = is1 ? fmaf(-2.0f, r, 1.0f) : x;  // tanh = 1-2/(e^2x+1) ; default id
    y = is2 ? r : y;                           // sigmoid = 1/(1+e^-x)
    y = is4 ? e : y;                           // gaussian = e^{-x^2/2}
    float s = __sinf(x);
    y = is3 ? s : y;                           // sin
    return y;
}

template <bool GUARD>
__global__ void __launch_bounds__(BLK, 4) cppn_mfma(
    const float* __restrict__ xin, const float* __restrict__ bin,
    const float* __restrict__ W1, const float* __restrict__ b1, const int* __restrict__ a1,
    const float* __restrict__ W2, const float* __restrict__ b2, const int* __restrict__ a2,
    const float* __restrict__ W3, const float* __restrict__ b3, const int* __restrict__ a3,
    const float* __restrict__ Wo, const float* __restrict__ bo,
    float* __restrict__ out, int Ppix, int pxBase) {
    const int tid = threadIdx.x;
    const int lane = tid & 63;
    const int wid = tid >> 6;
    const int q = lane >> 4;
    const int l15 = lane & 15;

    // ---- fragment construction (one-time per wave, amortized over 256 px) ----
    short8v w1f[2], w2f[2], w3f[2], wof;
#pragma unroll
    for (int t = 0; t < 2; ++t) {
#pragma unroll
        for (int j = 0; j < 8; ++j) {
            int k1 = 8 * q + j;  // mu1 k-mapping (inputs), k=12 -> bias row
            float v1 = (k1 < NIN) ? W1[k1 * HID + 16 * t + l15]
                     : (k1 == NIN ? b1[16 * t + l15] : 0.0f);
            w1f[t][j] = (short)f2bf(v1);
            int kk = 16 * (j >> 2) + 4 * q + (j & 3);  // mu2 k-mapping = D layout
            w2f[t][j] = (short)f2bf(W2[kk * HID + 16 * t + l15]);
            w3f[t][j] = (short)f2bf(W3[kk * HID + 16 * t + l15]);
        }
    }
#pragma unroll
    for (int j = 0; j < 8; ++j) {
        int kk = 16 * (j >> 2) + 4 * q + (j & 3);
        wof[j] = (l15 < NOUT) ? (short)f2bf(Wo[kk * NOUT + l15]) : (short)0;
    }

    f32x4 b2f[2], b3f[2], bof;
    unsigned av1 = 0, av2 = 0, av3 = 0;  // per-lane 4-bit act ids per D-element
#pragma unroll
    for (int e = 0; e < 8; ++e) {
        int t = e >> 2, r = e & 3;
        int idx = 16 * t + 4 * q + r;  // D-slot node index
        b2f[t][r] = b2[idx];
        b3f[t][r] = b3[idx];
        av1 |= (unsigned)(a1[idx] & 15) << (4 * e);
        av2 |= (unsigned)(a2[idx] & 15) << (4 * e);
        av3 |= (unsigned)(a3[idx] & 15) << (4 * e);
    }
#pragma unroll
    for (int r = 0; r < 4; ++r) bof[r] = (q == 0 && r < NOUT) ? bo[r] : 0.0f;

    auto actpack = [&](f32x4 p0, f32x4 p1, unsigned av) -> uint4v {
        float h[8];
#pragma unroll
        for (int e = 0; e < 8; ++e) {
            float x = (e < 4) ? p0[e] : p1[e - 4];
            h[e] = act_chain(x, (int)((av >> (4 * e)) & 15u));
        }
        uint4v w;
        w[0] = cvt_pk(h[0], h[1]); w[1] = cvt_pk(h[2], h[3]);
        w[2] = cvt_pk(h[4], h[5]); w[3] = cvt_pk(h[6], h[7]);
        return w;
    };

    float binv[8];
#pragma unroll
    for (int j = 0; j < 8; ++j) {
        int k = 8 * q + j;
        binv[j] = (k < NIN) ? bin[k] : 0.0f;
    }

    const long long wIdx = (long long)blockIdx.x * (BLK / 64) + wid;
    const long long px0 = (long long)pxBase + wIdx * (NT * 16);
    const float* __restrict__ xbase = xin + px0 * NIN;
    float* __restrict__ obase = out + px0 * 3;
    const f32x4 z = {0.0f, 0.0f, 0.0f, 0.0f};

#pragma unroll 1
    for (int it = 0; it < NT; ++it) {
        const int po = it * 16 + l15;
        const bool ok = !GUARD || (px0 + po < (long long)Ppix);

        uint4v b0w = {0, 0, 0, 0};
        if (q == 0) {
            if (ok) {
                const float4* ip = reinterpret_cast<const float4*>(xbase + po * NIN);
                float4 xa = ip[0], xb = ip[1];
                b0w[0] = cvt_pk(xa.x + binv[0], xa.y + binv[1]);
                b0w[1] = cvt_pk(xa.z + binv[2], xa.w + binv[3]);
                b0w[2] = cvt_pk(xb.x + binv[4], xb.y + binv[5]);
                b0w[3] = cvt_pk(xb.z + binv[6], xb.w + binv[7]);
            }
        } else if (q == 1) {
            if (ok) {
                float4 xc = reinterpret_cast<const float4*>(xbase + po * NIN)[2];
                b0w[0] = cvt_pk(xc.x + binv[0], xc.y + binv[1]);
                b0w[1] = cvt_pk(xc.z + binv[2], xc.w + binv[3]);
            }
            b0w[2] = 0x3F80u;  // constant-1 bias row (k=12)
        }

        short8v hb = __builtin_bit_cast(short8v, b0w);
        f32x4 p0 = __builtin_amdgcn_mfma_f32_16x16x32_bf16(w1f[0], hb, z, 0, 0, 0);
        f32x4 p1 = __builtin_amdgcn_mfma_f32_16x16x32_bf16(w1f[1], hb, z, 0, 0, 0);

        hb = __builtin_bit_cast(short8v, actpack(p0, p1, av1));
        p0 = __builtin_amdgcn_mfma_f32_16x16x32_bf16(w2f[0], hb, b2f[0], 0, 0, 0);
        p1 = __builtin_amdgcn_mfma_f32_16x16x32_bf16(w2f[1], hb, b2f[1], 0, 0, 0);

        hb = __builtin_bit_cast(short8v, actpack(p0, p1, av2));
        p0 = __builtin_amdgcn_mfma_f32_16x16x32_bf16(w3f[0], hb, b3f[0], 0, 0, 0);
        p1 = __builtin_amdgcn_mfma_f32_16x16x32_bf16(w3f[1], hb, b3f[1], 0, 0, 0);

        hb = __builtin_bit_cast(short8v, actpack(p0, p1, av3));
        f32x4 o4 = __builtin_amdgcn_mfma_f32_16x16x32_bf16(wof, hb, bof, 0, 0, 0);

        if (q == 0 && ok) {
            float* op = obase + po * 3;
            op[0] = tanh_fast(o4[0]);
            op[1] = tanh_fast(o4[1]);
            op[2] = tanh_fast(o4[2]);
        }
    }
}

extern "C" void kernel_launch(void* const* d_in, const int* in_sizes, int n_in,
                              void* d_out, int out_size, void* d_ws, size_t ws_size,
                              hipStream_t stream) {
    (void)n_in; (void)out_size; (void)d_ws; (void)ws_size;
    const float* xin = (const float*)d_in[0];
    const float* bin = (const float*)d_in[1];
    const float* W1  = (const float*)d_in[2];
    const float* b1  = (const float*)d_in[3];
    const int*   a1  = (const int*)  d_in[4];
    const float* W2  = (const float*)d_in[5];
    const float* b2  = (const float*)d_in[6];
    const int*   a2  = (const int*)  d_in[7];
    const float* W3  = (const float*)d_in[8];
    const float* b3  = (const float*)d_in[9];
    const int*   a3  = (const int*)  d_in[10];
    const float* Wo  = (const float*)d_in[11];
    const float* bo  = (const float*)d_in[12];
    float* out = (float*)d_out;

    const int Ppix = in_sizes[0] / NIN;
    const int pxPerBlock = (BLK / 64) * NT * 16;  // 1024
    const int fullBlocks = Ppix / pxPerBlock;
    const int rem = Ppix - fullBlocks * pxPerBlock;
    if (fullBlocks > 0)
        hipLaunchKernelGGL((cppn_mfma<false>), dim3(fullBlocks), dim3(BLK), 0, stream,
                           xin, bin, W1, b1, a1, W2, b2, a2, W3, b3, a3, Wo, bo,
                           out, Ppix, 0);
    if (rem > 0)
        hipLaunchKernelGGL((cppn_mfma<true>), dim3(1), dim3(BLK), 0, stream,
                           xin, bin, W1, b1, a1, W2, b2, a2, W3, b3, a3, Wo, bo,
                           out, Ppix, fullBlocks * pxPerBlock);
}

// Round 12
// 177.319 us; speedup vs baseline: 1.4403x; 1.0687x over previous
//
#include <hip/hip_runtime.h>
#include <hip/hip_bf16.h>

// CPPN via bf16 MFMA, round 11:
// r10 post-mortem: exp2f lowers to libm __ocml_exp2_f32 (~10+ instrs), NOT
// v_exp — busy-time went 67->83us vs r7. Fix A: revert to native __expf
// (v_mul+v_exp, proven r4-r7). Fix B: #pragma unroll 2 on the tile loop for
// 2x ILP (occupancy reads ~2.4 waves/SIMD; serial pack->MFMA->act chains may
// be latency-bound). Counters separate the theories: busy-time drop => A,
// busy-% up + dur down => B.

#define BLK 256
#define NT 16  // 16-pixel tiles per wave -> 256 px/wave, 1024 px/block

constexpr int NIN = 12, HID = 32, NOUT = 3;

typedef __attribute__((ext_vector_type(8))) short short8v;
typedef __attribute__((ext_vector_type(4))) float f32x4;
typedef __attribute__((ext_vector_type(4))) unsigned uint4v;

__device__ __forceinline__ unsigned short f2bf(float f) {  // setup only
    unsigned u = __builtin_bit_cast(unsigned, f);
    u += 0x7FFFu + ((u >> 16) & 1u);  // RNE
    return (unsigned short)(u >> 16);
}

// Single-instruction packed f32->bf16x2 (RNE on gfx950).
__device__ __forceinline__ unsigned cvt_pk(float lo, float hi) {
    unsigned r;
    asm("v_cvt_pk_bf16_f32 %0, %1, %2" : "=v"(r) : "v"(lo), "v"(hi));
    return r;
}

__device__ __forceinline__ float tanh_fast(float x) {
    float e = __expf(2.0f * x);
    return 1.0f - 2.0f * __builtin_amdgcn_rcpf(e + 1.0f);
}

// Branchless select-chain, native transcendentals only:
// __expf = v_mul(log2e)+v_exp ; __sinf = native sin ; rcp = v_rcp.
__device__ __forceinline__ float act_chain(float x, int sid) {
    const bool is1 = (sid == 1), is2 = (sid == 2), is3 = (sid == 3), is4 = (sid == 4);
    float ein = is1 ? (x + x) : -x;          // tanh: 2x ; sig/id/sin: -x
    float g = (x * -0.5f) * x;               // gauss: -x^2/2
    ein = is4 ? g : ein;
    float e = __expf(ein);                   // native v_exp path
    float r = __builtin_amdgcn_rcpf(e + 1.0f);
    float y = is1 ? fmaf(-2.0f, r, 1.0f) : x;  // tanh = 1-2/(e^2x+1) ; default id
    y = is2 ? r : y;                           // sigmoid = 1/(1+e^-x)
    y = is4 ? e : y;                           // gaussian
    float s = __sinf(x);
    y = is3 ? s : y;                           // sin
    return y;
}

template <bool GUARD>
__global__ void __launch_bounds__(BLK, 4) cppn_mfma(
    const float* __restrict__ xin, const float* __restrict__ bin,
    const float* __restrict__ W1, const float* __restrict__ b1, const int* __restrict__ a1,
    const float* __restrict__ W2, const float* __restrict__ b2, const int* __restrict__ a2,
    const float* __restrict__ W3, const float* __restrict__ b3, const int* __restrict__ a3,
    const float* __restrict__ Wo, const float* __restrict__ bo,
    float* __restrict__ out, int Ppix, int pxBase) {
    const int tid = threadIdx.x;
    const int lane = tid & 63;
    const int wid = tid >> 6;
    const int q = lane >> 4;
    const int l15 = lane & 15;

    // ---- fragment construction (one-time per wave, amortized over 256 px) ----
    short8v w1f[2], w2f[2], w3f[2], wof;
#pragma unroll
    for (int t = 0; t < 2; ++t) {
#pragma unroll
        for (int j = 0; j < 8; ++j) {
            int k1 = 8 * q + j;  // mu1 k-mapping (inputs), k=12 -> bias row
            float v1 = (k1 < NIN) ? W1[k1 * HID + 16 * t + l15]
                     : (k1 == NIN ? b1[16 * t + l15] : 0.0f);
            w1f[t][j] = (short)f2bf(v1);
            int kk = 16 * (j >> 2) + 4 * q + (j & 3);  // mu2 k-mapping = D layout
            w2f[t][j] = (short)f2bf(W2[kk * HID + 16 * t + l15]);
            w3f[t][j] = (short)f2bf(W3[kk * HID + 16 * t + l15]);
        }
    }
#pragma unroll
    for (int j = 0; j < 8; ++j) {
        int kk = 16 * (j >> 2) + 4 * q + (j & 3);
        wof[j] = (l15 < NOUT) ? (short)f2bf(Wo[kk * NOUT + l15]) : (short)0;
    }

    f32x4 b2f[2], b3f[2], bof;
    unsigned av1 = 0, av2 = 0, av3 = 0;  // per-lane 4-bit act ids per D-element
#pragma unroll
    for (int e = 0; e < 8; ++e) {
        int t = e >> 2, r = e & 3;
        int idx = 16 * t + 4 * q + r;  // D-slot node index
        b2f[t][r] = b2[idx];
        b3f[t][r] = b3[idx];
        av1 |= (unsigned)(a1[idx] & 15) << (4 * e);
        av2 |= (unsigned)(a2[idx] & 15) << (4 * e);
        av3 |= (unsigned)(a3[idx] & 15) << (4 * e);
    }
#pragma unroll
    for (int r = 0; r < 4; ++r) bof[r] = (q == 0 && r < NOUT) ? bo[r] : 0.0f;

    auto actpack = [&](f32x4 p0, f32x4 p1, unsigned av) -> uint4v {
        float h[8];
#pragma unroll
        for (int e = 0; e < 8; ++e) {
            float x = (e < 4) ? p0[e] : p1[e - 4];
            h[e] = act_chain(x, (int)((av >> (4 * e)) & 15u));
        }
        uint4v w;
        w[0] = cvt_pk(h[0], h[1]); w[1] = cvt_pk(h[2], h[3]);
        w[2] = cvt_pk(h[4], h[5]); w[3] = cvt_pk(h[6], h[7]);
        return w;
    };

    float binv[8];
#pragma unroll
    for (int j = 0; j < 8; ++j) {
        int k = 8 * q + j;
        binv[j] = (k < NIN) ? bin[k] : 0.0f;
    }

    const long long wIdx = (long long)blockIdx.x * (BLK / 64) + wid;
    const long long px0 = (long long)pxBase + wIdx * (NT * 16);
    const float* __restrict__ xbase = xin + px0 * NIN;
    float* __restrict__ obase = out + px0 * 3;
    const f32x4 z = {0.0f, 0.0f, 0.0f, 0.0f};

#pragma unroll 2
    for (int it = 0; it < NT; ++it) {
        const int po = it * 16 + l15;
        const bool ok = !GUARD || (px0 + po < (long long)Ppix);

        uint4v b0w = {0, 0, 0, 0};
        if (q == 0) {
            if (ok) {
                const float4* ip = reinterpret_cast<const float4*>(xbase + po * NIN);
                float4 xa = ip[0], xb = ip[1];
                b0w[0] = cvt_pk(xa.x + binv[0], xa.y + binv[1]);
                b0w[1] = cvt_pk(xa.z + binv[2], xa.w + binv[3]);
                b0w[2] = cvt_pk(xb.x + binv[4], xb.y + binv[5]);
                b0w[3] = cvt_pk(xb.z + binv[6], xb.w + binv[7]);
            }
        } else if (q == 1) {
            if (ok) {
                float4 xc = reinterpret_cast<const float4*>(xbase + po * NIN)[2];
                b0w[0] = cvt_pk(xc.x + binv[0], xc.y + binv[1]);
                b0w[1] = cvt_pk(xc.z + binv[2], xc.w + binv[3]);
            }
            b0w[2] = 0x3F80u;  // constant-1 bias row (k=12)
        }

        short8v hb = __builtin_bit_cast(short8v, b0w);
        f32x4 p0 = __builtin_amdgcn_mfma_f32_16x16x32_bf16(w1f[0], hb, z, 0, 0, 0);
        f32x4 p1 = __builtin_amdgcn_mfma_f32_16x16x32_bf16(w1f[1], hb, z, 0, 0, 0);

        hb = __builtin_bit_cast(short8v, actpack(p0, p1, av1));
        p0 = __builtin_amdgcn_mfma_f32_16x16x32_bf16(w2f[0], hb, b2f[0], 0, 0, 0);
        p1 = __builtin_amdgcn_mfma_f32_16x16x32_bf16(w2f[1], hb, b2f[1], 0, 0, 0);

        hb = __builtin_bit_cast(short8v, actpack(p0, p1, av2));
        p0 = __builtin_amdgcn_mfma_f32_16x16x32_bf16(w3f[0], hb, b3f[0], 0, 0, 0);
        p1 = __builtin_amdgcn_mfma_f32_16x16x32_bf16(w3f[1], hb, b3f[1], 0, 0, 0);

        hb = __builtin_bit_cast(short8v, actpack(p0, p1, av3));
        f32x4 o4 = __builtin_amdgcn_mfma_f32_16x16x32_bf16(wof, hb, bof, 0, 0, 0);

        if (q == 0 && ok) {
            float* op = obase + po * 3;
            op[0] = tanh_fast(o4[0]);
            op[1] = tanh_fast(o4[1]);
            op[2] = tanh_fast(o4[2]);
        }
    }
}

extern "C" void kernel_launch(void* const* d_in, const int* in_sizes, int n_in,
                              void* d_out, int out_size, void* d_ws, size_t ws_size,
                              hipStream_t stream) {
    (void)n_in; (void)out_size; (void)d_ws; (void)ws_size;
    const float* xin = (const float*)d_in[0];
    const float* bin = (const float*)d_in[1];
    const float* W1  = (const float*)d_in[2];
    const float* b1  = (const float*)d_in[3];
    const int*   a1  = (const int*)  d_in[4];
    const float* W2  = (const float*)d_in[5];
    const float* b2  = (const float*)d_in[6];
    const int*   a2  = (const int*)  d_in[7];
    const float* W3  = (const float*)d_in[8];
    const float* b3  = (const float*)d_in[9];
    const int*   a3  = (const int*)  d_in[10];
    const float* Wo  = (const float*)d_in[11];
    const float* bo  = (const float*)d_in[12];
    float* out = (float*)d_out;

    const int Ppix = in_sizes[0] / NIN;
    const int pxPerBlock = (BLK / 64) * NT * 16;  // 1024
    const int fullBlocks = Ppix / pxPerBlock;
    const int rem = Ppix - fullBlocks * pxPerBlock;
    if (fullBlocks > 0)
        hipLaunchKernelGGL((cppn_mfma<false>), dim3(fullBlocks), dim3(BLK), 0, stream,
                           xin, bin, W1, b1, a1, W2, b2, a2, W3, b3, a3, Wo, bo,
                           out, Ppix, 0);
    if (rem > 0)
        hipLaunchKernelGGL((cppn_mfma<true>), dim3(1), dim3(BLK), 0, stream,
                           xin, bin, W1, b1, a1, W2, b2, a2, W3, b3, a3, Wo, bo,
                           out, Ppix, fullBlocks * pxPerBlock);
}

// Round 13
// 176.222 us; speedup vs baseline: 1.4493x; 1.0062x over previous
//
#include <hip/hip_runtime.h>
#include <hip/hip_bf16.h>

// CPPN via bf16 MFMA, round 13:
// (1) Transcendentals via raw inline asm (v_exp_f32 = 2^x with log2e folded
//     at source; v_sin_f32 takes revolutions -> one mul by 1/2pi; v_rcp_f32).
//     Eliminates any residual libm path by construction (r10 showed exp2f
//     silently went libm; this makes instruction count deterministic).
// (2) Tile loop unroll 4 (unroll 2 was r12's proven ILP win; 26% of cycles
//     still idle at occupancy ~2.4 waves/SIMD -> more independent chains).
// Tripwire: FETCH_SIZE > 30MB => unroll-4 spilled, revert next round.

#define BLK 256
#define NT 16  // 16-pixel tiles per wave -> 256 px/wave, 1024 px/block

constexpr int NIN = 12, HID = 32, NOUT = 3;

typedef __attribute__((ext_vector_type(8))) short short8v;
typedef __attribute__((ext_vector_type(4))) float f32x4;
typedef __attribute__((ext_vector_type(4))) unsigned uint4v;

__device__ __forceinline__ unsigned short f2bf(float f) {  // setup only
    unsigned u = __builtin_bit_cast(unsigned, f);
    u += 0x7FFFu + ((u >> 16) & 1u);  // RNE
    return (unsigned short)(u >> 16);
}

// Single-instruction packed f32->bf16x2 (RNE on gfx950).
__device__ __forceinline__ unsigned cvt_pk(float lo, float hi) {
    unsigned r;
    asm("v_cvt_pk_bf16_f32 %0, %1, %2" : "=v"(r) : "v"(lo), "v"(hi));
    return r;
}

// Raw hardware transcendentals — deterministic codegen.
__device__ __forceinline__ float v_exp2(float x) {  // 2^x
    float r; asm("v_exp_f32 %0, %1" : "=v"(r) : "v"(x)); return r;
}
__device__ __forceinline__ float v_sin_rev(float x) {  // sin(2*pi*x)
    float r; asm("v_sin_f32 %0, %1" : "=v"(r) : "v"(x)); return r;
}
__device__ __forceinline__ float v_rcp(float x) {
    float r; asm("v_rcp_f32 %0, %1" : "=v"(r) : "v"(x)); return r;
}

#define LOG2E 1.4426950408889634f
#define INV2PI 0.15915494309189535f

__device__ __forceinline__ float tanh_fast(float x) {
    // tanh = 1 - 2/(2^(2Lx)+1)
    float e = v_exp2((2.0f * LOG2E) * x);
    return fmaf(-2.0f, v_rcp(e + 1.0f), 1.0f);
}

// Branchless select-chain, all-native ops (~21 VALU deterministic):
// shared 2^ein for tanh/sigmoid/gauss, one v_sin, 4 cmp + 5 cndmask.
__device__ __forceinline__ float act_chain(float x, int sid) {
    const bool is1 = (sid == 1), is2 = (sid == 2), is3 = (sid == 3), is4 = (sid == 4);
    float u = x * LOG2E;
    float ein = is1 ? (u + u) : -u;          // tanh: 2Lx ; sig/id/sin: -Lx
    float g = (u * -0.5f) * x;               // gauss: -0.5*L*x^2
    ein = is4 ? g : ein;
    float e = v_exp2(ein);
    float r = v_rcp(e + 1.0f);
    float y = is1 ? fmaf(-2.0f, r, 1.0f) : x;  // tanh ; default identity
    y = is2 ? r : y;                           // sigmoid
    y = is4 ? e : y;                           // gaussian
    float s = v_sin_rev(x * INV2PI);
    y = is3 ? s : y;                           // sin
    return y;
}

template <bool GUARD>
__global__ void __launch_bounds__(BLK, 4) cppn_mfma(
    const float* __restrict__ xin, const float* __restrict__ bin,
    const float* __restrict__ W1, const float* __restrict__ b1, const int* __restrict__ a1,
    const float* __restrict__ W2, const float* __restrict__ b2, const int* __restrict__ a2,
    const float* __restrict__ W3, const float* __restrict__ b3, const int* __restrict__ a3,
    const float* __restrict__ Wo, const float* __restrict__ bo,
    float* __restrict__ out, int Ppix, int pxBase) {
    const int tid = threadIdx.x;
    const int lane = tid & 63;
    const int wid = tid >> 6;
    const int q = lane >> 4;
    const int l15 = lane & 15;

    // ---- fragment construction (one-time per wave, amortized over 256 px) ----
    short8v w1f[2], w2f[2], w3f[2], wof;
#pragma unroll
    for (int t = 0; t < 2; ++t) {
#pragma unroll
        for (int j = 0; j < 8; ++j) {
            int k1 = 8 * q + j;  // mu1 k-mapping (inputs), k=12 -> bias row
            float v1 = (k1 < NIN) ? W1[k1 * HID + 16 * t + l15]
                     : (k1 == NIN ? b1[16 * t + l15] : 0.0f);
            w1f[t][j] = (short)f2bf(v1);
            int kk = 16 * (j >> 2) + 4 * q + (j & 3);  // mu2 k-mapping = D layout
            w2f[t][j] = (short)f2bf(W2[kk * HID + 16 * t + l15]);
            w3f[t][j] = (short)f2bf(W3[kk * HID + 16 * t + l15]);
        }
    }
#pragma unroll
    for (int j = 0; j < 8; ++j) {
        int kk = 16 * (j >> 2) + 4 * q + (j & 3);
        wof[j] = (l15 < NOUT) ? (short)f2bf(Wo[kk * NOUT + l15]) : (short)0;
    }

    f32x4 b2f[2], b3f[2], bof;
    unsigned av1 = 0, av2 = 0, av3 = 0;  // per-lane 4-bit act ids per D-element
#pragma unroll
    for (int e = 0; e < 8; ++e) {
        int t = e >> 2, r = e & 3;
        int idx = 16 * t + 4 * q + r;  // D-slot node index
        b2f[t][r] = b2[idx];
        b3f[t][r] = b3[idx];
        av1 |= (unsigned)(a1[idx] & 15) << (4 * e);
        av2 |= (unsigned)(a2[idx] & 15) << (4 * e);
        av3 |= (unsigned)(a3[idx] & 15) << (4 * e);
    }
#pragma unroll
    for (int r = 0; r < 4; ++r) bof[r] = (q == 0 && r < NOUT) ? bo[r] : 0.0f;

    auto actpack = [&](f32x4 p0, f32x4 p1, unsigned av) -> uint4v {
        float h[8];
#pragma unroll
        for (int e = 0; e < 8; ++e) {
            float x = (e < 4) ? p0[e] : p1[e - 4];
            h[e] = act_chain(x, (int)((av >> (4 * e)) & 15u));
        }
        uint4v w;
        w[0] = cvt_pk(h[0], h[1]); w[1] = cvt_pk(h[2], h[3]);
        w[2] = cvt_pk(h[4], h[5]); w[3] = cvt_pk(h[6], h[7]);
        return w;
    };

    float binv[8];
#pragma unroll
    for (int j = 0; j < 8; ++j) {
        int k = 8 * q + j;
        binv[j] = (k < NIN) ? bin[k] : 0.0f;
    }

    const long long wIdx = (long long)blockIdx.x * (BLK / 64) + wid;
    const long long px0 = (long long)pxBase + wIdx * (NT * 16);
    const float* __restrict__ xbase = xin + px0 * NIN;
    float* __restrict__ obase = out + px0 * 3;
    const f32x4 z = {0.0f, 0.0f, 0.0f, 0.0f};

#pragma unroll 4
    for (int it = 0; it < NT; ++it) {
        const int po = it * 16 + l15;
        const bool ok = !GUARD || (px0 + po < (long long)Ppix);

        uint4v b0w = {0, 0, 0, 0};
        if (q == 0) {
            if (ok) {
                const float4* ip = reinterpret_cast<const float4*>(xbase + po * NIN);
                float4 xa = ip[0], xb = ip[1];
                b0w[0] = cvt_pk(xa.x + binv[0], xa.y + binv[1]);
                b0w[1] = cvt_pk(xa.z + binv[2], xa.w + binv[3]);
                b0w[2] = cvt_pk(xb.x + binv[4], xb.y + binv[5]);
                b0w[3] = cvt_pk(xb.z + binv[6], xb.w + binv[7]);
            }
        } else if (q == 1) {
            if (ok) {
                float4 xc = reinterpret_cast<const float4*>(xbase + po * NIN)[2];
                b0w[0] = cvt_pk(xc.x + binv[0], xc.y + binv[1]);
                b0w[1] = cvt_pk(xc.z + binv[2], xc.w + binv[3]);
            }
            b0w[2] = 0x3F80u;  // constant-1 bias row (k=12)
        }

        short8v hb = __builtin_bit_cast(short8v, b0w);
        f32x4 p0 = __builtin_amdgcn_mfma_f32_16x16x32_bf16(w1f[0], hb, z, 0, 0, 0);
        f32x4 p1 = __builtin_amdgcn_mfma_f32_16x16x32_bf16(w1f[1], hb, z, 0, 0, 0);

        hb = __builtin_bit_cast(short8v, actpack(p0, p1, av1));
        p0 = __builtin_amdgcn_mfma_f32_16x16x32_bf16(w2f[0], hb, b2f[0], 0, 0, 0);
        p1 = __builtin_amdgcn_mfma_f32_16x16x32_bf16(w2f[1], hb, b2f[1], 0, 0, 0);

        hb = __builtin_bit_cast(short8v, actpack(p0, p1, av2));
        p0 = __builtin_amdgcn_mfma_f32_16x16x32_bf16(w3f[0], hb, b3f[0], 0, 0, 0);
        p1 = __builtin_amdgcn_mfma_f32_16x16x32_bf16(w3f[1], hb, b3f[1], 0, 0, 0);

        hb = __builtin_bit_cast(short8v, actpack(p0, p1, av3));
        f32x4 o4 = __builtin_amdgcn_mfma_f32_16x16x32_bf16(wof, hb, bof, 0, 0, 0);

        if (q == 0 && ok) {
            float* op = obase + po * 3;
            op[0] = tanh_fast(o4[0]);
            op[1] = tanh_fast(o4[1]);
            op[2] = tanh_fast(o4[2]);
        }
    }
}

extern "C" void kernel_launch(void* const* d_in, const int* in_sizes, int n_in,
                              void* d_out, int out_size, void* d_ws, size_t ws_size,
                              hipStream_t stream) {
    (void)n_in; (void)out_size; (void)d_ws; (void)ws_size;
    const float* xin = (const float*)d_in[0];
    const float* bin = (const float*)d_in[1];
    const float* W1  = (const float*)d_in[2];
    const float* b1  = (const float*)d_in[3];
    const int*   a1  = (const int*)  d_in[4];
    const float* W2  = (const float*)d_in[5];
    const float* b2  = (const float*)d_in[6];
    const int*   a2  = (const int*)  d_in[7];
    const float* W3  = (const float*)d_in[8];
    const float* b3  = (const float*)d_in[9];
    const int*   a3  = (const int*)  d_in[10];
    const float* Wo  = (const float*)d_in[11];
    const float* bo  = (const float*)d_in[12];
    float* out = (float*)d_out;

    const int Ppix = in_sizes[0] / NIN;
    const int pxPerBlock = (BLK / 64) * NT * 16;  // 1024
    const int fullBlocks = Ppix / pxPerBlock;
    const int rem = Ppix - fullBlocks * pxPerBlock;
    if (fullBlocks > 0)
        hipLaunchKernelGGL((cppn_mfma<false>), dim3(fullBlocks), dim3(BLK), 0, stream,
                           xin, bin, W1, b1, a1, W2, b2, a2, W3, b3, a3, Wo, bo,
                           out, Ppix, 0);
    if (rem > 0)
        hipLaunchKernelGGL((cppn_mfma<true>), dim3(1), dim3(BLK), 0, stream,
                           xin, bin, W1, b1, a1, W2, b2, a2, W3, b3, a3, Wo, bo,
                           out, Ppix, fullBlocks * pxPerBlock);
}